// Round 8
// baseline (727.846 us; speedup 1.0000x reference)
//
#include <hip/hip_runtime.h>
#include <math.h>

#define NB 32
#define NH 480
#define NW 640
#define HW (NH*NW)
#define BHW (NB*HW)
#define CAP 16384
#define TOPK 1024
#define NMS_T 0.3f
#define TX 64
#define TY 16
#define TXH (TX+4)   // 68: halo-2 tile width
#define TYH (TY+4)   // 20
#define TXM (TX+6)   // 70: halo-3 mask tile width
#define TYM (TY+6)   // 22

struct GaussK { float g[25]; };

__device__ __forceinline__ bool analytic_mask(
    float xf, float yf, float h0, float h1, float h2, float h3, float h4,
    float h5, float h6, float h7, float h8)
{
    float w0 = h0 * xf + h1 * yf + h2;
    float w1 = h3 * xf + h4 * yf + h5;
    float wz = h6 * xf + h7 * yf + h8;
    float z = wz + 1e-8f;
    float px = w0 / z, py = w1 / z;
    float x0f = floorf(px), y0f = floorf(py);
    float wx = px - x0f, wy = py - y0f;
    int x0 = (int)x0f, y0 = (int)y0f;
    bool vx0 = (x0 >= 0) && (x0 <= NW - 1);
    bool vx1 = (x0 + 1 >= 0) && (x0 + 1 <= NW - 1);
    bool vy0 = (y0 >= 0) && (y0 <= NH - 1);
    bool vy1 = (y0 + 1 >= 0) && (y0 + 1 <= NH - 1);
    return (vx0 && vy0)
        || (wx > 0.f && vx1 && vy0)
        || (wy > 0.f && vx0 && vy1)
        || (wx > 0.f && wy > 0.f && vx1 && vy1);
}

// ===== fused: analytic mask + erode + masked s1/warp in LDS + 5x5 NMS =======
__global__ __launch_bounds__(256) void prepnms_kernel(
    const float* __restrict__ s1, const float* __restrict__ s2,
    const float* __restrict__ homo, float* __restrict__ mask_out,
    unsigned long long* __restrict__ cand, int* __restrict__ cntp,
    unsigned int* __restrict__ normbuck)
{
    __shared__ float smA[TYH * TXH];            // masked s1, halo 2
    __shared__ float smB[TYH * TXH];            // masked warp, halo 2
    __shared__ unsigned char msk[TYM * TXM];    // analytic mask, halo 3
    __shared__ unsigned char emk[TY * TX];      // eroded mask, interior
    __shared__ int wsum[4];
    __shared__ int base_sh;

    int tlin = blockIdx.x, b = blockIdx.y;
    int tyi = tlin / (NW / TX), txi = tlin - tyi * (NW / TX);
    int bx0 = txi * TX, by0 = tyi * TY;
    int tid = threadIdx.x, lane = tid & 63, wv = tid >> 6;

    const float* h = homo + b * 9;
    float h0 = h[0], h1 = h[1], h2 = h[2], h3 = h[3], h4 = h[4];
    float h5 = h[5], h6 = h[6], h7 = h[7], h8 = h[8];

    // analytic mask, halo 3 (no image reads)
    for (int i = tid; i < TYM * TXM; i += 256) {
        int ly = i / TXM, lx = i - ly * TXM;
        int gy = by0 + ly - 3, gx = bx0 + lx - 3;
        int m = 0;
        if (gy >= 0 && gy < NH && gx >= 0 && gx < NW)
            m = analytic_mask((float)gx, (float)gy, h0, h1, h2, h3, h4, h5, h6, h7, h8) ? 1 : 0;
        msk[i] = (unsigned char)m;
    }
    __syncthreads();

    // masked s1 + masked warp on halo-2 grid
    const float* img1 = s1 + (size_t)b * HW;
    const float* img2 = s2 + (size_t)b * HW;
    for (int i = tid; i < TYH * TXH; i += 256) {
        int ly = i / TXH, lx = i - ly * TXH;
        int gy = by0 + ly - 2, gx = bx0 + lx - 2;
        float a = -1e30f, wval = -1e30f;
        if (gy >= 0 && gy < NH && gx >= 0 && gx < NW) {
            int em;
            if (gx == 0 || gx == NW - 1 || gy == 0 || gy == NH - 1) {
                em = 0;
            } else {
                // msk cell of (gy,gx) is (ly+1, lx+1); 3x3 starts at (ly, lx)
                const unsigned char* q = &msk[ly * TXM + lx];
                em = q[0] & q[1] & q[2]
                   & q[TXM] & q[TXM + 1] & q[TXM + 2]
                   & q[2 * TXM] & q[2 * TXM + 1] & q[2 * TXM + 2];
            }
            float emf = (float)em;
            float xf = (float)gx, yf = (float)gy;
            float w0 = h0 * xf + h1 * yf + h2;
            float w1 = h3 * xf + h4 * yf + h5;
            float wz = h6 * xf + h7 * yf + h8;
            float z = wz + 1e-8f;
            float px = w0 / z, py = w1 / z;
            float x0f = floorf(px), y0f = floorf(py);
            float wx = px - x0f, wyf = py - y0f;
            int x0 = (int)x0f, y0 = (int)y0f;
            bool vx0 = (x0 >= 0) && (x0 <= NW - 1);
            bool vx1 = (x0 + 1 >= 0) && (x0 + 1 <= NW - 1);
            bool vy0 = (y0 >= 0) && (y0 <= NH - 1);
            bool vy1 = (y0 + 1 >= 0) && (y0 + 1 <= NH - 1);
            float v00 = (vx0 && vy0) ? img2[y0 * NW + x0] : 0.f;
            float v01 = (vx1 && vy0) ? img2[y0 * NW + x0 + 1] : 0.f;
            float v10 = (vx0 && vy1) ? img2[(y0 + 1) * NW + x0] : 0.f;
            float v11 = (vx1 && vy1) ? img2[(y0 + 1) * NW + x0 + 1] : 0.f;
            float val = v00 * (1.f - wx) * (1.f - wyf)
                      + v01 * wx * (1.f - wyf)
                      + v10 * (1.f - wx) * wyf
                      + v11 * wx * wyf;
            a = img1[gy * NW + gx] * emf;
            wval = val * emf;
            if (ly >= 2 && ly < TYH - 2 && lx >= 2 && lx < TXH - 2)
                emk[(ly - 2) * TX + (lx - 2)] = (unsigned char)em;
        }
        smA[i] = a;
        smB[i] = wval;
    }
    __syncthreads();

    // interior: mask output + norm count
    int cnt = 0;
    {
        int tx = lane;
#pragma unroll
        for (int r = 0; r < 4; ++r) {
            int tyy = wv * 4 + r;
            int em = emk[tyy * TX + tx];
            mask_out[(size_t)b * HW + (by0 + tyy) * NW + bx0 + tx] = (float)em;
            cnt += em;
        }
    }
    for (int off = 32; off; off >>= 1) cnt += __shfl_down(cnt, off, 64);
    if (lane == 0) wsum[wv] = cnt;
    __syncthreads();
    if (tid == 0) {
        int bid = blockIdx.y * 300 + blockIdx.x;
        atomicAdd(&normbuck[(bid & 255) * 16],
                  (unsigned int)(wsum[0] + wsum[1] + wsum[2] + wsum[3]));
    }
    __syncthreads(); // wsum reused below

    // NMS on both fields from LDS
    int tx = lane, ty0 = wv * 4;
    for (int f = 0; f < 2; ++f) {
        const float* tile = f ? smB : smA;
        unsigned long long keys[4];
        int slot[4];
        int wtot = 0;
#pragma unroll
        for (int r = 0; r < 4; ++r) {
            int ty = ty0 + r;
            float c = tile[(ty + 2) * TXH + tx + 2];
            bool pk = false;
            if (c > NMS_T) {
                float m = -1e30f;
#pragma unroll
                for (int dy = 0; dy < 5; ++dy)
#pragma unroll
                    for (int dx = 0; dx < 5; ++dx)
                        m = fmaxf(m, tile[(ty + dy) * TXH + tx + dx]);
                pk = (m <= c); // window max == c  <=>  (score == pooled)
            }
            unsigned long long bal = __ballot(pk);
            if (pk) {
                int rem = (by0 + ty) * NW + bx0 + tx;
                keys[r] = ((unsigned long long)__float_as_uint(c) << 32) |
                          (unsigned long long)(0xFFFFFFFFu - (unsigned int)rem);
                slot[r] = wtot + (int)__popcll(bal & ((1ull << lane) - 1ull));
            } else {
                slot[r] = -1;
            }
            wtot += (int)__popcll(bal);
        }
        if (lane == 0) wsum[wv] = wtot;
        __syncthreads();
        if (tid == 0)
            base_sh = atomicAdd(&cntp[(f * NB + b) * 16],
                                wsum[0] + wsum[1] + wsum[2] + wsum[3]);
        __syncthreads();
        int wbase = base_sh;
        for (int i2 = 0; i2 < wv; ++i2) wbase += wsum[i2];
        unsigned long long* dst = cand + (size_t)(f * NB + b) * CAP;
#pragma unroll
        for (int r = 0; r < 4; ++r)
            if (slot[r] >= 0) {
                int p = wbase + slot[r];
                if (p < CAP) dst[p] = keys[r];
            }
        if (f == 0) __syncthreads();
    }
}

// ===== bucket-select exact top-1024; field0 -> ordered kp, field1 -> list ===
// bucket = (valbits>>12) - 0x3E999 : monotonic in value for v in (0.3, 1.0]
__global__ __launch_bounds__(1024) void select_kernel(
    const unsigned long long* __restrict__ cand, const int* __restrict__ cntp,
    float* __restrict__ out, unsigned long long* __restrict__ list)
{
    __shared__ unsigned int hist[4096];
    __shared__ unsigned int cnt2[4096];
    __shared__ unsigned int scn[4097];
    __shared__ unsigned long long sel[TOPK];
    __shared__ unsigned long long tbuf[1024];
    __shared__ unsigned int ws16[16];
    __shared__ int sh_T, sh_need;
    __shared__ unsigned int tcnt, selcnt;
    __shared__ unsigned long long sh_kstar;

    int blk = blockIdx.x;     // 0..63
    int field = blk >> 5;
    int b = blk & 31;
    int tid = threadIdx.x;
    int n = cntp[(field * NB + b) * 16];
    if (n > CAP) n = CAP;
    int selK = n < TOPK ? n : TOPK;
    const unsigned long long* src = cand + (size_t)(field * NB + b) * CAP;

    for (int i = tid; i < 4096; i += 1024) { hist[i] = 0; cnt2[i] = 0; }
    for (int i = tid; i < TOPK; i += 1024) sel[i] = 0ULL;
    if (tid == 0) { tcnt = 0; selcnt = 0; scn[4096] = 0; sh_T = 4095; sh_need = 0; }
    __syncthreads();

    for (int i = tid; i < n; i += 1024) {
        unsigned int vb = (unsigned int)(src[i] >> 32);
        atomicAdd(&hist[(vb >> 12) - 0x3E999u], 1u);
    }
    __syncthreads();

    // hierarchical suffix scan (thread owns bins 4t..4t+3)
    int base4 = tid * 4;
    unsigned int c0 = hist[base4], c1 = hist[base4 + 1];
    unsigned int c2 = hist[base4 + 2], c3 = hist[base4 + 3];
    unsigned int own = c0 + c1 + c2 + c3;
    unsigned int sfx = own;
    int lane = tid & 63, wv = tid >> 6;
    for (int off = 1; off < 64; off <<= 1) {
        unsigned int v = __shfl_down(sfx, off, 64);
        if (lane + off < 64) sfx += v;
    }
    if (lane == 0) ws16[wv] = sfx;
    __syncthreads();
    unsigned int wo = 0;
    for (int w = wv + 1; w < 16; ++w) wo += ws16[w];
    unsigned int excl = wo + (sfx - own);
    unsigned int s3 = excl + c3;
    unsigned int s2v = s3 + c2;
    unsigned int s1v = s2v + c1;
    unsigned int s0 = s1v + c0;
    scn[base4] = s0; scn[base4 + 1] = s1v;
    scn[base4 + 2] = s2v; scn[base4 + 3] = s3;
    __syncthreads();

    if (selK > 0) {
#pragma unroll
        for (int r = 0; r < 4; ++r) {
            int bin = base4 + r;
            unsigned int S = scn[bin], Sn = scn[bin + 1];
            if (S >= (unsigned int)selK && Sn < (unsigned int)selK) {
                sh_T = bin; sh_need = selK - (int)Sn;
            }
        }
    }
    __syncthreads();
    int T = sh_T, need = sh_need;

    for (int i = tid; i < n; i += 1024) {
        unsigned long long k = src[i];
        unsigned int vb = (unsigned int)(k >> 32);
        if ((int)((vb >> 12) - 0x3E999u) == T) {
            unsigned int p = atomicAdd(&tcnt, 1u);
            if (p < 1024) tbuf[p] = k;
        }
    }
    __syncthreads();
    if (tid == 0) {
        int m = tcnt > 1024u ? 1024 : (int)tcnt;
        for (int i = 1; i < m; ++i) {
            unsigned long long key = tbuf[i]; int j = i - 1;
            while (j >= 0 && tbuf[j] < key) { tbuf[j + 1] = tbuf[j]; --j; }
            tbuf[j + 1] = key;
        }
        sh_kstar = (need > 0) ? tbuf[need - 1] : ~0ULL;
    }
    __syncthreads();
    unsigned long long kstar = sh_kstar;

    if (field == 0) {
        // value-ordered placement + per-bucket fixup (exact reference order)
        for (int i = tid; i < n; i += 1024) {
            unsigned long long k = src[i];
            if (k >= kstar) {
                unsigned int vb = (unsigned int)(k >> 32);
                int bin = (int)((vb >> 12) - 0x3E999u);
                unsigned int pos = scn[bin + 1] + atomicAdd(&cnt2[bin], 1u);
                sel[pos] = k;
            }
        }
        __syncthreads();
        for (int bin = T + tid; bin < 4096; bin += 1024) {
            int len = (bin == T) ? need : (int)hist[bin];
            if (len >= 2) {
                unsigned int rb = scn[bin + 1];
                for (int i = 1; i < len; ++i) {
                    unsigned long long key = sel[rb + i]; int j = i - 1;
                    while (j >= 0 && sel[rb + j] < key) { sel[rb + j + 1] = sel[rb + j]; --j; }
                    sel[rb + j + 1] = key;
                }
            }
        }
        __syncthreads();
        if (tid < TOPK) {
            unsigned long long key = sel[tid];
            unsigned int vb = (unsigned int)(key >> 32);
            int idx = (int)(0xFFFFFFFFu - (unsigned int)key);
            if (vb == 0) idx = tid; // padding fallback (n < 1024, never in practice)
            int y = idx / NW, x = idx - y * NW;
            out[1 + ((size_t)b * TOPK + tid) * 2 + 0] = (float)y;
            out[1 + ((size_t)b * TOPK + tid) * 2 + 1] = (float)x;
        }
    } else {
        // order-independent: wave-aggregated arrival-order compaction
        int nloop = (n + 1023) / 1024;
        for (int it = 0; it < nloop; ++it) {
            int i = it * 1024 + tid;
            unsigned long long k = (i < n) ? src[i] : 0ULL;
            bool keep = (k >= kstar) && (k != 0ULL);
            unsigned long long bal = __ballot(keep);
            unsigned int wc = (unsigned int)__popcll(bal);
            unsigned int base = 0;
            if (lane == 0 && wc) base = atomicAdd(&selcnt, wc);
            base = __shfl(base, 0, 64);
            if (keep) {
                unsigned int p = base + (unsigned int)__popcll(bal & ((1ull << lane) - 1ull));
                if (p < TOPK) sel[p] = k;
            }
        }
        __syncthreads();
        for (int i = tid; i < TOPK; i += 1024)
            list[(size_t)b * TOPK + i] = sel[i];
    }
}

// ===== fused gaussian gather-stamp + analytic mask recompute + MSE loss =====
__global__ __launch_bounds__(256) void gloss_kernel(
    const float* __restrict__ s1, const float* __restrict__ homo,
    const unsigned long long* __restrict__ list, double* __restrict__ lbuck,
    GaussK gk)
{
    __shared__ float gt[TY * TX];                 // 4 KiB
    __shared__ unsigned char msk1[(TY + 2) * (TX + 2)];
    __shared__ double wsd[4];
    int tlin = blockIdx.x, b = blockIdx.y;
    int tyi = tlin / (NW / TX), txi = tlin - tyi * (NW / TX);
    int bx0 = txi * TX, by0 = tyi * TY;
    int tid = threadIdx.x, lane = tid & 63, wv = tid >> 6;

    const float* h = homo + b * 9;
    float h0 = h[0], h1 = h[1], h2 = h[2], h3 = h[3], h4 = h[4];
    float h5 = h[5], h6 = h[6], h7 = h[7], h8 = h[8];

    for (int i = tid; i < TY * TX; i += 256) gt[i] = 0.f;
    for (int i = tid; i < (TY + 2) * (TX + 2); i += 256) {
        int ly = i / (TX + 2), lx = i - ly * (TX + 2);
        int gy = by0 + ly - 1, gx = bx0 + lx - 1;
        int m = 0;
        if (gy >= 0 && gy < NH && gx >= 0 && gx < NW)
            m = analytic_mask((float)gx, (float)gy, h0, h1, h2, h3, h4, h5, h6, h7, h8) ? 1 : 0;
        msk1[i] = (unsigned char)m;
    }
    __syncthreads();

    // gather-stamp peaks overlapping this tile
    const unsigned long long* lst = list + (size_t)b * TOPK;
    for (int i = tid; i < TOPK; i += 256) {
        unsigned long long k = lst[i];
        unsigned int vb = (unsigned int)(k >> 32);
        if (!vb) continue;
        int idx = (int)(0xFFFFFFFFu - (unsigned int)k);
        int y = idx / NW, x = idx - y * NW;
        int ry = y - by0, rx = x - bx0;
        if (rx < -2 || rx > TX + 1 || ry < -2 || ry > TY + 1) continue;
        float v = __uint_as_float(vb);
#pragma unroll
        for (int dy = -2; dy <= 2; ++dy) {
            int yy = ry + dy;
            if (yy < 0 || yy >= TY) continue;
#pragma unroll
            for (int dx = -2; dx <= 2; ++dx) {
                int xx = rx + dx;
                if (xx < 0 || xx >= TX) continue;
                atomicAdd(&gt[yy * TX + xx], v * gk.g[(dy + 2) * 5 + (dx + 2)]);
            }
        }
    }
    __syncthreads();

    double acc = 0.0;
    int tx = lane;
#pragma unroll
    for (int r = 0; r < 4; ++r) {
        int tyy = wv * 4 + r;
        int gy = by0 + tyy, gx = bx0 + tx;
        int em;
        if (gx == 0 || gx == NW - 1 || gy == 0 || gy == NH - 1) {
            em = 0;
        } else {
            const unsigned char* q = &msk1[tyy * (TX + 2) + tx];
            em = q[0] & q[1] & q[2]
               & q[TX + 2] & q[TX + 3] & q[TX + 4]
               & q[2 * (TX + 2)] & q[2 * (TX + 2) + 1] & q[2 * (TX + 2) + 2];
        }
        float sv = s1[(size_t)b * HW + gy * NW + gx] * (float)em;
        float d = sv - gt[tyy * TX + tx];
        acc += (double)(d * d);
    }
    for (int off = 32; off; off >>= 1) acc += __shfl_down(acc, off, 64);
    if (lane == 0) wsd[wv] = acc;
    __syncthreads();
    if (tid == 0) {
        int bid = blockIdx.y * 300 + blockIdx.x;
        atomicAdd(&lbuck[(bid & 63) * 8], wsd[0] + wsd[1] + wsd[2] + wsd[3]);
    }
}

__global__ __launch_bounds__(256) void final_kernel(
    const double* __restrict__ lbp, const unsigned int* __restrict__ nbp,
    float* __restrict__ out)
{
    __shared__ double ds[4];
    __shared__ unsigned int us[4];
    int tid = threadIdx.x, lane = tid & 63, wv = tid >> 6;
    unsigned int nv = nbp[tid * 16];
    double lv = (tid < 64) ? lbp[tid * 8] : 0.0;
    for (int off = 32; off; off >>= 1) {
        nv += __shfl_down(nv, off, 64);
        lv += __shfl_down(lv, off, 64);
    }
    if (lane == 0) { us[wv] = nv; ds[wv] = lv; }
    __syncthreads();
    if (tid == 0) {
        double t = ds[0] + ds[1] + ds[2] + ds[3];
        unsigned long long nn = (unsigned long long)us[0] + us[1] + us[2] + us[3];
        out[0] = (float)(t / (double)nn);
    }
}

// ---------------------------------------------------------------- launch
extern "C" void kernel_launch(void* const* d_in, const int* in_sizes, int n_in,
                              void* d_out, int out_size, void* d_ws, size_t ws_size,
                              hipStream_t stream)
{
    const float* s1 = (const float*)d_in[0];
    const float* s2 = (const float*)d_in[1];
    const float* homo = (const float*)d_in[2];
    float* out = (float*)d_out;

    char* ws = (char*)d_ws;
    unsigned long long* cand = (unsigned long long*)ws;          // 8 MiB
    size_t off = (size_t)2 * NB * CAP * 8;
    unsigned long long* list = (unsigned long long*)(ws + off);  // 256 KiB
    off += (size_t)NB * TOPK * 8;
    int* cntp = (int*)(ws + off);                         // 64 * 64B  = 4 KiB
    unsigned int* nbp = (unsigned int*)(ws + off + 4096); // 256 * 64B = 16 KiB
    double* lbp = (double*)(ws + off + 20480);            // 64 * 64B  = 4 KiB

    float* mask_out = out + 1 + (size_t)NB * TOPK * 2;

    // gaussian 5x5 sigma=2 coefficients, f64 math to match numpy
    GaussK gk;
    {
        double gg[5];
        for (int i = 0; i < 5; ++i) {
            double ax = (double)i - 2.0;
            gg[i] = ::exp(-(ax * ax) / 8.0);
        }
        double tot = 0.0;
        for (int i = 0; i < 5; ++i)
            for (int j = 0; j < 5; ++j) tot += gg[i] * gg[j];
        for (int i = 0; i < 5; ++i)
            for (int j = 0; j < 5; ++j)
                gk.g[i * 5 + j] = (float)(gg[i] * gg[j] / tot);
    }

    hipMemsetAsync(cntp, 0, 24576, stream); // cntp + nbp + lbp
    prepnms_kernel<<<dim3(300, NB), 256, 0, stream>>>(s1, s2, homo, mask_out, cand, cntp, nbp);
    select_kernel<<<64, 1024, 0, stream>>>(cand, cntp, out, list);
    gloss_kernel<<<dim3(300, NB), 256, 0, stream>>>(s1, homo, list, lbp, gk);
    final_kernel<<<1, 256, 0, stream>>>(lbp, nbp, out);
}

// Round 10
// 306.723 us; speedup vs baseline: 2.3730x; 2.3730x over previous
//
#include <hip/hip_runtime.h>
#include <math.h>

#define NB 32
#define NH 480
#define NW 640
#define HW (NH*NW)
#define BHW (NB*HW)
#define CAP 16384
#define TOPK 1024
#define NMS_T 0.3f
#define TX 64
#define TY 16
#define TXH (TX+4)   // 68: halo-2 tile width
#define TYH (TY+4)   // 20
#define TXM (TX+6)   // 70: halo-3 mask tile width
#define TYM (TY+6)   // 22

struct GaussK { float g[25]; };

__device__ __forceinline__ bool analytic_mask(
    float xf, float yf, float h0, float h1, float h2, float h3, float h4,
    float h5, float h6, float h7, float h8)
{
    float w0 = h0 * xf + h1 * yf + h2;
    float w1 = h3 * xf + h4 * yf + h5;
    float wz = h6 * xf + h7 * yf + h8;
    float z = wz + 1e-8f;
    float px = w0 / z, py = w1 / z;
    float x0f = floorf(px), y0f = floorf(py);
    float wx = px - x0f, wy = py - y0f;
    int x0 = (int)x0f, y0 = (int)y0f;
    bool vx0 = (x0 >= 0) && (x0 <= NW - 1);
    bool vx1 = (x0 + 1 >= 0) && (x0 + 1 <= NW - 1);
    bool vy0 = (y0 >= 0) && (y0 <= NH - 1);
    bool vy1 = (y0 + 1 >= 0) && (y0 + 1 <= NH - 1);
    return (vx0 && vy0)
        || (wx > 0.f && vx1 && vy0)
        || (wy > 0.f && vx0 && vy1)
        || (wx > 0.f && wy > 0.f && vx1 && vy1);
}

// ===== fused: analytic mask + erode + masked s1/warp in LDS + 5x5 NMS =======
__global__ __launch_bounds__(256) void prepnms_kernel(
    const float* __restrict__ s1, const float* __restrict__ s2,
    const float* __restrict__ homo, float* __restrict__ mask_out,
    unsigned long long* __restrict__ cand, int* __restrict__ cntp,
    unsigned int* __restrict__ normbuck)
{
    __shared__ float smA[TYH * TXH];            // masked s1, halo 2
    __shared__ float smB[TYH * TXH];            // masked warp, halo 2
    __shared__ unsigned char msk[TYM * TXM];    // analytic mask, halo 3
    __shared__ unsigned char emk[TY * TX];      // eroded mask, interior
    __shared__ int wsum[4];
    __shared__ int base_sh;

    int tlin = blockIdx.x, b = blockIdx.y;
    int tyi = tlin / (NW / TX), txi = tlin - tyi * (NW / TX);
    int bx0 = txi * TX, by0 = tyi * TY;
    int tid = threadIdx.x, lane = tid & 63, wv = tid >> 6;

    const float* h = homo + b * 9;
    float h0 = h[0], h1 = h[1], h2 = h[2], h3 = h[3], h4 = h[4];
    float h5 = h[5], h6 = h[6], h7 = h[7], h8 = h[8];

    // analytic mask, halo 3 (no image reads)
    for (int i = tid; i < TYM * TXM; i += 256) {
        int ly = i / TXM, lx = i - ly * TXM;
        int gy = by0 + ly - 3, gx = bx0 + lx - 3;
        int m = 0;
        if (gy >= 0 && gy < NH && gx >= 0 && gx < NW)
            m = analytic_mask((float)gx, (float)gy, h0, h1, h2, h3, h4, h5, h6, h7, h8) ? 1 : 0;
        msk[i] = (unsigned char)m;
    }
    __syncthreads();

    // masked s1 + masked warp on halo-2 grid
    const float* img1 = s1 + (size_t)b * HW;
    const float* img2 = s2 + (size_t)b * HW;
    for (int i = tid; i < TYH * TXH; i += 256) {
        int ly = i / TXH, lx = i - ly * TXH;
        int gy = by0 + ly - 2, gx = bx0 + lx - 2;
        float a = -1e30f, wval = -1e30f;
        if (gy >= 0 && gy < NH && gx >= 0 && gx < NW) {
            int em;
            if (gx == 0 || gx == NW - 1 || gy == 0 || gy == NH - 1) {
                em = 0;
            } else {
                // msk cell of (gy,gx) is (ly+1, lx+1); 3x3 starts at (ly, lx)
                const unsigned char* q = &msk[ly * TXM + lx];
                em = q[0] & q[1] & q[2]
                   & q[TXM] & q[TXM + 1] & q[TXM + 2]
                   & q[2 * TXM] & q[2 * TXM + 1] & q[2 * TXM + 2];
            }
            float emf = (float)em;
            float xf = (float)gx, yf = (float)gy;
            float w0 = h0 * xf + h1 * yf + h2;
            float w1 = h3 * xf + h4 * yf + h5;
            float wz = h6 * xf + h7 * yf + h8;
            float z = wz + 1e-8f;
            float px = w0 / z, py = w1 / z;
            float x0f = floorf(px), y0f = floorf(py);
            float wx = px - x0f, wyf = py - y0f;
            int x0 = (int)x0f, y0 = (int)y0f;
            bool vx0 = (x0 >= 0) && (x0 <= NW - 1);
            bool vx1 = (x0 + 1 >= 0) && (x0 + 1 <= NW - 1);
            bool vy0 = (y0 >= 0) && (y0 <= NH - 1);
            bool vy1 = (y0 + 1 >= 0) && (y0 + 1 <= NH - 1);
            float v00 = (vx0 && vy0) ? img2[y0 * NW + x0] : 0.f;
            float v01 = (vx1 && vy0) ? img2[y0 * NW + x0 + 1] : 0.f;
            float v10 = (vx0 && vy1) ? img2[(y0 + 1) * NW + x0] : 0.f;
            float v11 = (vx1 && vy1) ? img2[(y0 + 1) * NW + x0 + 1] : 0.f;
            float val = v00 * (1.f - wx) * (1.f - wyf)
                      + v01 * wx * (1.f - wyf)
                      + v10 * (1.f - wx) * wyf
                      + v11 * wx * wyf;
            a = img1[gy * NW + gx] * emf;
            wval = val * emf;
            if (ly >= 2 && ly < TYH - 2 && lx >= 2 && lx < TXH - 2)
                emk[(ly - 2) * TX + (lx - 2)] = (unsigned char)em;
        }
        smA[i] = a;
        smB[i] = wval;
    }
    __syncthreads();

    // interior: mask output + norm count
    int cnt = 0;
    {
        int tx = lane;
#pragma unroll
        for (int r = 0; r < 4; ++r) {
            int tyy = wv * 4 + r;
            int em = emk[tyy * TX + tx];
            mask_out[(size_t)b * HW + (by0 + tyy) * NW + bx0 + tx] = (float)em;
            cnt += em;
        }
    }
    for (int off = 32; off; off >>= 1) cnt += __shfl_down(cnt, off, 64);
    if (lane == 0) wsum[wv] = cnt;
    __syncthreads();
    if (tid == 0) {
        int bid = blockIdx.y * 300 + blockIdx.x;
        atomicAdd(&normbuck[(bid & 255) * 16],
                  (unsigned int)(wsum[0] + wsum[1] + wsum[2] + wsum[3]));
    }
    __syncthreads(); // wsum reused below

    // NMS on both fields from LDS
    int tx = lane, ty0 = wv * 4;
    for (int f = 0; f < 2; ++f) {
        const float* tile = f ? smB : smA;
        unsigned long long keys[4];
        int slot[4];
        int wtot = 0;
#pragma unroll
        for (int r = 0; r < 4; ++r) {
            int ty = ty0 + r;
            float c = tile[(ty + 2) * TXH + tx + 2];
            bool pk = false;
            if (c > NMS_T) {
                float m = -1e30f;
#pragma unroll
                for (int dy = 0; dy < 5; ++dy)
#pragma unroll
                    for (int dx = 0; dx < 5; ++dx)
                        m = fmaxf(m, tile[(ty + dy) * TXH + tx + dx]);
                pk = (m <= c); // window max == c  <=>  (score == pooled)
            }
            unsigned long long bal = __ballot(pk);
            if (pk) {
                int rem = (by0 + ty) * NW + bx0 + tx;
                keys[r] = ((unsigned long long)__float_as_uint(c) << 32) |
                          (unsigned long long)(0xFFFFFFFFu - (unsigned int)rem);
                slot[r] = wtot + (int)__popcll(bal & ((1ull << lane) - 1ull));
            } else {
                slot[r] = -1;
            }
            wtot += (int)__popcll(bal);
        }
        if (lane == 0) wsum[wv] = wtot;
        __syncthreads();
        if (tid == 0)
            base_sh = atomicAdd(&cntp[(f * NB + b) * 16],
                                wsum[0] + wsum[1] + wsum[2] + wsum[3]);
        __syncthreads();
        int wbase = base_sh;
        for (int i2 = 0; i2 < wv; ++i2) wbase += wsum[i2];
        unsigned long long* dst = cand + (size_t)(f * NB + b) * CAP;
#pragma unroll
        for (int r = 0; r < 4; ++r)
            if (slot[r] >= 0) {
                int p = wbase + slot[r];
                if (p < CAP) dst[p] = keys[r];
            }
        if (f == 0) __syncthreads();
    }
}

// ===== R5-proven radix-select top-1024 (exact); f0 -> sorted kp, f1 -> list =
__global__ __launch_bounds__(1024) void select_kernel(
    const unsigned long long* __restrict__ cand, const int* __restrict__ cntp,
    float* __restrict__ out, unsigned long long* __restrict__ list)
{
    __shared__ unsigned long long keys[CAP];   // 128 KiB
    __shared__ unsigned int hist[2048];        // 8 KiB
    __shared__ unsigned int scn[2048];         // 8 KiB
    __shared__ unsigned long long sel[TOPK];   // 8 KiB
    __shared__ int sh_T, sh_need;
    __shared__ unsigned int selcnt;

    int blk = blockIdx.x;     // 0..63
    int field = blk >> 5;
    int b = blk & 31;
    int tid = threadIdx.x;
    int n = cntp[(field * NB + b) * 16];
    if (n > CAP) n = CAP;
    const unsigned long long* src = cand + (size_t)(field * NB + b) * CAP;
    for (int i = tid; i < n; i += 1024) keys[i] = src[i];
    for (int i = tid; i < TOPK; i += 1024) sel[i] = 0ULL;
    if (tid == 0) selcnt = 0;
    __syncthreads();

    unsigned long long kstar = 1ULL; // n<=TOPK: select all real keys
    if (n > TOPK) {
        unsigned long long prefix = 0ULL;
        int need = TOPK;
        const int shifts[6] = {53, 42, 31, 20, 9, 0};
        const int widths[6] = {11, 11, 11, 11, 11, 9};
        for (int p = 0; p < 6; ++p) {
            int sh = shifts[p], wdt = widths[p];
            int nb2 = 1 << wdt;
            unsigned int mk = (unsigned int)nb2 - 1u;
            int shp = (p == 0) ? 63 : (sh + wdt); // avoid shift-by-64 UB
            for (int i = tid; i < nb2; i += 1024) hist[i] = 0;
            __syncthreads();
            for (int i = tid; i < n; i += 1024) {
                unsigned long long k = keys[i];
                bool act = (p == 0) || ((k >> shp) == prefix);
                if (act) atomicAdd(&hist[(unsigned int)(k >> sh) & mk], 1u);
            }
            __syncthreads();
            // suffix sums: sp[i] = count of active keys with bin >= i
            unsigned int* sp = hist;
            unsigned int* dp = scn;
            for (int d = 1; d < nb2; d <<= 1) {
                for (int i = tid; i < nb2; i += 1024)
                    dp[i] = sp[i] + ((i + d < nb2) ? sp[i + d] : 0u);
                __syncthreads();
                unsigned int* t = sp; sp = dp; dp = t;
            }
            for (int i = tid; i < nb2; i += 1024) {
                unsigned int hi = sp[i];
                unsigned int ab = (i + 1 < nb2) ? sp[i + 1] : 0u;
                if (ab < (unsigned int)need && (unsigned int)need <= hi) {
                    sh_T = i;
                    sh_need = need - (int)ab;
                }
            }
            __syncthreads();
            prefix = (prefix << wdt) | (unsigned long long)sh_T;
            need = sh_need;
            __syncthreads();
        }
        kstar = prefix; // exact 1024th-largest key (keys unique)
    }

    // gather survivors (exactly min(n,TOPK) of them)
    for (int i = tid; i < n; i += 1024) {
        unsigned long long k = keys[i];
        if (k >= kstar) {
            unsigned int pos = atomicAdd(&selcnt, 1u);
            if (pos < TOPK) sel[pos] = k;
        }
    }
    __syncthreads();

    if (field == 0) {
        // order matters for kp output: bitonic sort 1024 (desc)
        for (int k2 = 2; k2 <= TOPK; k2 <<= 1) {
            for (int j = k2 >> 1; j > 0; j >>= 1) {
                int t = tid;
                if (t < TOPK / 2) {
                    int i = ((t & ~(j - 1)) << 1) | (t & (j - 1));
                    int ixj = i | j;
                    bool desc = ((i & k2) == 0);
                    unsigned long long a = sel[i], c = sel[ixj];
                    if ((a < c) == desc) { sel[i] = c; sel[ixj] = a; }
                }
                __syncthreads();
            }
        }
        if (tid < TOPK) {
            unsigned long long key = sel[tid];
            unsigned int vb = (unsigned int)(key >> 32);
            int idx = (int)(0xFFFFFFFFu - (unsigned int)key);
            if (vb == 0) idx = tid; // padding fallback
            int y = idx / NW, x = idx - y * NW;
            out[1 + ((size_t)b * TOPK + tid) * 2 + 0] = (float)y;
            out[1 + ((size_t)b * TOPK + tid) * 2 + 1] = (float)x;
        }
    } else {
        // order-independent: arrival-order list for the gather-stamp pass
        for (int i = tid; i < TOPK; i += 1024)
            list[(size_t)b * TOPK + i] = sel[i];
    }
}

// ===== fused gaussian gather-stamp + analytic mask recompute + MSE loss =====
__global__ __launch_bounds__(256) void gloss_kernel(
    const float* __restrict__ s1, const float* __restrict__ homo,
    const unsigned long long* __restrict__ list, double* __restrict__ lbuck,
    GaussK gk)
{
    __shared__ float gt[TY * TX];                 // 4 KiB
    __shared__ unsigned char msk1[(TY + 2) * (TX + 2)];
    __shared__ double wsd[4];
    int tlin = blockIdx.x, b = blockIdx.y;
    int tyi = tlin / (NW / TX), txi = tlin - tyi * (NW / TX);
    int bx0 = txi * TX, by0 = tyi * TY;
    int tid = threadIdx.x, lane = tid & 63, wv = tid >> 6;

    const float* h = homo + b * 9;
    float h0 = h[0], h1 = h[1], h2 = h[2], h3 = h[3], h4 = h[4];
    float h5 = h[5], h6 = h[6], h7 = h[7], h8 = h[8];

    for (int i = tid; i < TY * TX; i += 256) gt[i] = 0.f;
    for (int i = tid; i < (TY + 2) * (TX + 2); i += 256) {
        int ly = i / (TX + 2), lx = i - ly * (TX + 2);
        int gy = by0 + ly - 1, gx = bx0 + lx - 1;
        int m = 0;
        if (gy >= 0 && gy < NH && gx >= 0 && gx < NW)
            m = analytic_mask((float)gx, (float)gy, h0, h1, h2, h3, h4, h5, h6, h7, h8) ? 1 : 0;
        msk1[i] = (unsigned char)m;
    }
    __syncthreads();

    // gather-stamp peaks overlapping this tile
    const unsigned long long* lst = list + (size_t)b * TOPK;
    for (int i = tid; i < TOPK; i += 256) {
        unsigned long long k = lst[i];
        unsigned int vb = (unsigned int)(k >> 32);
        if (!vb) continue;
        int idx = (int)(0xFFFFFFFFu - (unsigned int)k);
        int y = idx / NW, x = idx - y * NW;
        int ry = y - by0, rx = x - bx0;
        if (rx < -2 || rx > TX + 1 || ry < -2 || ry > TY + 1) continue;
        float v = __uint_as_float(vb);
#pragma unroll
        for (int dy = -2; dy <= 2; ++dy) {
            int yy = ry + dy;
            if (yy < 0 || yy >= TY) continue;
#pragma unroll
            for (int dx = -2; dx <= 2; ++dx) {
                int xx = rx + dx;
                if (xx < 0 || xx >= TX) continue;
                atomicAdd(&gt[yy * TX + xx], v * gk.g[(dy + 2) * 5 + (dx + 2)]);
            }
        }
    }
    __syncthreads();

    double acc = 0.0;
    int tx = lane;
#pragma unroll
    for (int r = 0; r < 4; ++r) {
        int tyy = wv * 4 + r;
        int gy = by0 + tyy, gx = bx0 + tx;
        int em;
        if (gx == 0 || gx == NW - 1 || gy == 0 || gy == NH - 1) {
            em = 0;
        } else {
            const unsigned char* q = &msk1[tyy * (TX + 2) + tx];
            em = q[0] & q[1] & q[2]
               & q[TX + 2] & q[TX + 3] & q[TX + 4]
               & q[2 * (TX + 2)] & q[2 * (TX + 2) + 1] & q[2 * (TX + 2) + 2];
        }
        float sv = s1[(size_t)b * HW + gy * NW + gx] * (float)em;
        float d = sv - gt[tyy * TX + tx];
        acc += (double)(d * d);
    }
    for (int off = 32; off; off >>= 1) acc += __shfl_down(acc, off, 64);
    if (lane == 0) wsd[wv] = acc;
    __syncthreads();
    if (tid == 0) {
        int bid = blockIdx.y * 300 + blockIdx.x;
        atomicAdd(&lbuck[(bid & 63) * 8], wsd[0] + wsd[1] + wsd[2] + wsd[3]);
    }
}

__global__ __launch_bounds__(256) void final_kernel(
    const double* __restrict__ lbp, const unsigned int* __restrict__ nbp,
    float* __restrict__ out)
{
    __shared__ double ds[4];
    __shared__ unsigned int us[4];
    int tid = threadIdx.x, lane = tid & 63, wv = tid >> 6;
    unsigned int nv = nbp[tid * 16];
    double lv = (tid < 64) ? lbp[tid * 8] : 0.0;
    for (int off = 32; off; off >>= 1) {
        nv += __shfl_down(nv, off, 64);
        lv += __shfl_down(lv, off, 64);
    }
    if (lane == 0) { us[wv] = nv; ds[wv] = lv; }
    __syncthreads();
    if (tid == 0) {
        double t = ds[0] + ds[1] + ds[2] + ds[3];
        unsigned long long nn = (unsigned long long)us[0] + us[1] + us[2] + us[3];
        out[0] = (float)(t / (double)nn);
    }
}

// ---------------------------------------------------------------- launch
extern "C" void kernel_launch(void* const* d_in, const int* in_sizes, int n_in,
                              void* d_out, int out_size, void* d_ws, size_t ws_size,
                              hipStream_t stream)
{
    const float* s1 = (const float*)d_in[0];
    const float* s2 = (const float*)d_in[1];
    const float* homo = (const float*)d_in[2];
    float* out = (float*)d_out;

    char* ws = (char*)d_ws;
    unsigned long long* cand = (unsigned long long*)ws;          // 8 MiB
    size_t off = (size_t)2 * NB * CAP * 8;
    unsigned long long* list = (unsigned long long*)(ws + off);  // 256 KiB
    off += (size_t)NB * TOPK * 8;
    int* cntp = (int*)(ws + off);                         // 64 * 64B  = 4 KiB
    unsigned int* nbp = (unsigned int*)(ws + off + 4096); // 256 * 64B = 16 KiB
    double* lbp = (double*)(ws + off + 20480);            // 64 * 64B  = 4 KiB

    float* mask_out = out + 1 + (size_t)NB * TOPK * 2;

    // gaussian 5x5 sigma=2 coefficients, f64 math to match numpy
    GaussK gk;
    {
        double gg[5];
        for (int i = 0; i < 5; ++i) {
            double ax = (double)i - 2.0;
            gg[i] = ::exp(-(ax * ax) / 8.0);
        }
        double tot = 0.0;
        for (int i = 0; i < 5; ++i)
            for (int j = 0; j < 5; ++j) tot += gg[i] * gg[j];
        for (int i = 0; i < 5; ++i)
            for (int j = 0; j < 5; ++j)
                gk.g[i * 5 + j] = (float)(gg[i] * gg[j] / tot);
    }

    hipMemsetAsync(cntp, 0, 24576, stream); // cntp + nbp + lbp
    prepnms_kernel<<<dim3(300, NB), 256, 0, stream>>>(s1, s2, homo, mask_out, cand, cntp, nbp);
    select_kernel<<<64, 1024, 0, stream>>>(cand, cntp, out, list);
    gloss_kernel<<<dim3(300, NB), 256, 0, stream>>>(s1, homo, list, lbp, gk);
    final_kernel<<<1, 256, 0, stream>>>(lbp, nbp, out);
}